// Round 4
// baseline (711.544 us; speedup 1.0000x reference)
//
#include <hip/hip_runtime.h>
#include <math.h>

// All tensors fp32. B=256, F=512, H=1024, C=1000.

// ---------------------------------------------------------------------------
// pool_big: wave per row, float4 loads, 8-deep unroll. ~122 us = ~86% of the
// beyond-L2 read ceiling (~3.2 TB/s combined L3+HBM). Known-good (R2).
// ---------------------------------------------------------------------------
struct Pool4Segs {
    const float* src[4];
    float*       dst[4];
    int n4[4];        // rowlen / 4
    int cum[4];       // inclusive prefix sum of rows
    float inv[4];
};

__global__ __launch_bounds__(256) void pool_big_kernel(Pool4Segs S, int total_waves) {
    int gid  = blockIdx.x * 256 + threadIdx.x;
    int wave = gid >> 6;
    int lane = gid & 63;
    if (wave >= total_waves) return;
    int s = 0;
    #pragma unroll
    for (int i = 0; i < 3; ++i) if (wave >= S.cum[i]) s = i + 1;
    int row = wave - (s == 0 ? 0 : S.cum[s - 1]);
    const int n4 = S.n4[s];
    const float4* p4 = (const float4*)(S.src[s]) + (size_t)row * n4;

    float a0 = 0.f, a1 = 0.f, a2 = 0.f, a3 = 0.f;
    float a4 = 0.f, a5 = 0.f, a6 = 0.f, a7 = 0.f;
    int k = lane;
    for (; k + 448 < n4; k += 512) {
        float4 v0 = p4[k];       float4 v1 = p4[k + 64];
        float4 v2 = p4[k + 128]; float4 v3 = p4[k + 192];
        float4 v4 = p4[k + 256]; float4 v5 = p4[k + 320];
        float4 v6 = p4[k + 384]; float4 v7 = p4[k + 448];
        a0 += (v0.x + v0.y) + (v0.z + v0.w);
        a1 += (v1.x + v1.y) + (v1.z + v1.w);
        a2 += (v2.x + v2.y) + (v2.z + v2.w);
        a3 += (v3.x + v3.y) + (v3.z + v3.w);
        a4 += (v4.x + v4.y) + (v4.z + v4.w);
        a5 += (v5.x + v5.y) + (v5.z + v5.w);
        a6 += (v6.x + v6.y) + (v6.z + v6.w);
        a7 += (v7.x + v7.y) + (v7.z + v7.w);
    }
    for (; k + 192 < n4; k += 256) {
        float4 v0 = p4[k];       float4 v1 = p4[k + 64];
        float4 v2 = p4[k + 128]; float4 v3 = p4[k + 192];
        a0 += (v0.x + v0.y) + (v0.z + v0.w);
        a1 += (v1.x + v1.y) + (v1.z + v1.w);
        a2 += (v2.x + v2.y) + (v2.z + v2.w);
        a3 += (v3.x + v3.y) + (v3.z + v3.w);
    }
    for (; k < n4; k += 64) {
        float4 v = p4[k];
        a0 += (v.x + v.y) + (v.z + v.w);
    }
    float acc = ((a0 + a1) + (a2 + a3)) + ((a4 + a5) + (a6 + a7));
    #pragma unroll
    for (int off = 32; off > 0; off >>= 1) acc += __shfl_down(acc, off, 64);
    if (lane == 0) S.dst[s][row] = acc * S.inv[s];
}

// ---------------------------------------------------------------------------
// pool_small: rowlen == 49 (s5 then ff). Block of 256 stages 64 rows into LDS
// via fully-unrolled float4 loads; 4 threads/row reduce. Known-good (R2).
// ---------------------------------------------------------------------------
__global__ __launch_bounds__(256) void pool_small_kernel(const float* __restrict__ s5,
        const float* __restrict__ ff, float* __restrict__ dst5, float* __restrict__ dstf,
        int rows5) {
    __shared__ float lds[64 * 49];
    const int tid  = threadIdx.x;
    const int row0 = blockIdx.x * 64;
    const float* src;
    float* dst;
    int rbase;
    if (row0 < rows5) { src = s5; dst = dst5; rbase = row0; }
    else              { src = ff; dst = dstf; rbase = row0 - rows5; }
    const float4* p4 = (const float4*)(src + (size_t)rbase * 49);
    float4* l4 = (float4*)lds;
    float4 v0 = p4[tid];
    float4 v1 = p4[tid + 256];
    float4 v2 = p4[tid + 512];
    float4 v3;
    const bool t3 = (tid < 784 - 768);
    if (t3) v3 = p4[tid + 768];
    l4[tid]       = v0;
    l4[tid + 256] = v1;
    l4[tid + 512] = v2;
    if (t3) l4[tid + 768] = v3;
    __syncthreads();
    const int r  = tid >> 2;
    const int c0 = tid & 3;
    float s = 0.f;
    #pragma unroll
    for (int c = c0; c < 49; c += 4) s += lds[r * 49 + c];
    s += __shfl_down(s, 2, 64);
    s += __shfl_down(s, 1, 64);
    if (c0 == 0) dst[rbase + r] = s * (1.f / 49.f);
}

// ---------------------------------------------------------------------------
// fc_splitk v2: ROWS=4 m-rows per wave, K stepped by 4. Per 4-k block:
// 4 X float4 loads (contiguous in k) + 4 W float4 loads -> 8 VMEM / 64 FMA.
// W L2 traffic = (M/4) * Wbytes. Kc % 4 == 0 guaranteed by host.
// Partials P[ks][M][N]; reduced deterministically by reduce_bias_kernel.
// ---------------------------------------------------------------------------
template <int ROWS>
__global__ __launch_bounds__(256) void fc_splitk_kernel(const float* __restrict__ X,
        const float* __restrict__ W, float* __restrict__ P,
        int M, int K, int N, int NW, int Kc, int total_waves) {
    int gid  = blockIdx.x * 256 + threadIdx.x;
    int wave = gid >> 6;
    int lane = gid & 63;
    if (wave >= total_waves) return;
    int wpk = (M / ROWS) * NW;
    int ks  = wave / wpk;
    int rem = wave - ks * wpk;
    int mg  = rem / NW;
    int nw  = rem - mg * NW;
    int n0  = nw * 256 + lane * 4;
    int m0  = mg * ROWS;
    const bool nok = (n0 < N);          // N % 4 == 0 for all layers
    const int  n0s = nok ? n0 : 0;      // keep OOB lanes on a safe address
    int k0 = ks * Kc;
    int k1 = k0 + Kc; if (k1 > K) k1 = K;
    const float* xp = X + (size_t)m0 * K;
    const float* wp = W + n0s;
    float4 acc[ROWS];
    #pragma unroll
    for (int r = 0; r < ROWS; ++r) acc[r] = make_float4(0.f, 0.f, 0.f, 0.f);
    #pragma unroll 2
    for (int k = k0; k < k1; k += 4) {   // (k1-k0) % 4 == 0 (host guarantees)
        float4 xv[ROWS];
        #pragma unroll
        for (int r = 0; r < ROWS; ++r)
            xv[r] = *(const float4*)(xp + (size_t)r * K + k);
        float4 w0 = *(const float4*)(wp + (size_t)(k + 0) * N);
        float4 w1 = *(const float4*)(wp + (size_t)(k + 1) * N);
        float4 w2 = *(const float4*)(wp + (size_t)(k + 2) * N);
        float4 w3 = *(const float4*)(wp + (size_t)(k + 3) * N);
        #pragma unroll
        for (int r = 0; r < ROWS; ++r) {
            float4 a = acc[r];
            float4 x = xv[r];
            a.x += x.x * w0.x; a.y += x.x * w0.y; a.z += x.x * w0.z; a.w += x.x * w0.w;
            a.x += x.y * w1.x; a.y += x.y * w1.y; a.z += x.y * w1.z; a.w += x.y * w1.w;
            a.x += x.z * w2.x; a.y += x.z * w2.y; a.z += x.z * w2.z; a.w += x.z * w2.w;
            a.x += x.w * w3.x; a.y += x.w * w3.y; a.z += x.w * w3.z; a.w += x.w * w3.w;
            acc[r] = a;
        }
    }
    if (!nok) return;
    float* pp = P + ((size_t)ks * M + m0) * N + n0;
    #pragma unroll
    for (int r = 0; r < ROWS; ++r) *(float4*)(pp + (size_t)r * N) = acc[r];
}

// Sum KS partial slices + bias (+ReLU). float4 per thread; MN % 4 == 0.
__global__ __launch_bounds__(256) void reduce_bias_kernel(const float* __restrict__ P,
        const float* __restrict__ bias, float* __restrict__ Y,
        int MN, int N, int KS, int do_relu) {
    int i = (blockIdx.x * 256 + threadIdx.x) * 4;
    if (i >= MN) return;
    float4 a = *(const float4*)(P + i);
    for (int s = 1; s < KS; ++s) {
        float4 b = *(const float4*)(P + (size_t)s * MN + i);
        a.x += b.x; a.y += b.y; a.z += b.z; a.w += b.w;
    }
    int n = i - (i / N) * N;            // N % 4 == 0 -> no straddle
    float4 bb = *(const float4*)(bias + n);
    a.x += bb.x; a.y += bb.y; a.z += bb.z; a.w += bb.w;
    if (do_relu) {
        a.x = fmaxf(a.x, 0.f); a.y = fmaxf(a.y, 0.f);
        a.z = fmaxf(a.z, 0.f); a.w = fmaxf(a.w, 0.f);
    }
    *(float4*)(Y + i) = a;
}

// ---------------------------------------------------------------------------
// Gate fc3 (K=512 -> 5 logits) fused with top-2 + softmax. 4 waves per batch.
// jax.lax.top_k tie rule: lower index wins on equality (strict >).
// ---------------------------------------------------------------------------
__global__ __launch_bounds__(256) void fc3_top2_kernel(const float* __restrict__ X,
        const float* __restrict__ W, const float* __restrict__ bias,
        int* __restrict__ topi, float* __restrict__ wsm,
        float* __restrict__ out_gl, float* __restrict__ out_topi,
        float* __restrict__ out_w, int K) {
    const int b    = blockIdx.x;
    const int tid  = threadIdx.x;     // 0..255
    const int lane = tid & 63;
    const int wv   = tid >> 6;
    __shared__ float red[4][5];
    const float* x = X + (size_t)b * K;
    float acc[5] = {0.f, 0.f, 0.f, 0.f, 0.f};
    for (int k = tid; k < K; k += 256) {
        float xv = x[k];
        const float* wr = W + (size_t)k * 5;
        acc[0] += xv * wr[0]; acc[1] += xv * wr[1]; acc[2] += xv * wr[2];
        acc[3] += xv * wr[3]; acc[4] += xv * wr[4];
    }
    #pragma unroll
    for (int off = 32; off > 0; off >>= 1) {
        #pragma unroll
        for (int j = 0; j < 5; ++j) acc[j] += __shfl_down(acc[j], off, 64);
    }
    if (lane == 0) {
        #pragma unroll
        for (int j = 0; j < 5; ++j) red[wv][j] = acc[j];
    }
    __syncthreads();
    if (tid == 0) {
        float v[5];
        #pragma unroll
        for (int j = 0; j < 5; ++j)
            v[j] = ((red[0][j] + red[1][j]) + (red[2][j] + red[3][j])) + bias[j];
        int i0 = 0;
        #pragma unroll
        for (int i = 1; i < 5; ++i) if (v[i] > v[i0]) i0 = i;
        int i1 = -1;
        #pragma unroll
        for (int i = 0; i < 5; ++i) {
            if (i == i0) continue;
            if (i1 < 0 || v[i] > v[i1]) i1 = i;
        }
        float e1 = __expf(v[i1] - v[i0]);          // v[i0] is the max
        float inv = 1.f / (1.f + e1);
        float w0 = inv, w1 = e1 * inv;
        topi[b * 2] = i0; topi[b * 2 + 1] = i1;
        wsm[b * 2] = w0;  wsm[b * 2 + 1] = w1;
        #pragma unroll
        for (int j = 0; j < 5; ++j) out_gl[b * 5 + j] = v[j];
        out_topi[b * 2]     = (float)i0;
        out_topi[b * 2 + 1] = (float)i1;
        out_w[b * 2]     = w0;
        out_w[b * 2 + 1] = w1;
    }
}

// ---------------------------------------------------------------------------
// Per-batch: the two SELECTED stage projections (Linear + LayerNorm + exact
// GELU), softmax-weighted mixture. One block of 512 per batch element.
// ---------------------------------------------------------------------------
struct ProjParams {
    const float* W[5];
    const float* bp[5];
    const float* g[5];
    const float* be[5];
    int K[5];
    int poff[5];
};

__global__ __launch_bounds__(512) void proj_mix_kernel(ProjParams P,
        const float* __restrict__ pools, const int* __restrict__ topi,
        const float* __restrict__ wsm, float* __restrict__ mix) {
    const int b = blockIdx.x;
    const int f = threadIdx.x;           // 0..511
    __shared__ float sp[160];
    __shared__ float redS[8], redQ[8];
    __shared__ float s_mu, s_rstd;

    float acc = 0.f;
    for (int j = 0; j < 2; ++j) {
        __syncthreads();                 // protect sp / red reuse across iterations
        const int st = topi[b * 2 + j];
        const int K  = P.K[st];
        const float* p = pools + P.poff[st] + (size_t)b * K;
        if (f < K) sp[f] = p[f];
        __syncthreads();

        const float* W = P.W[st];
        float h0 = 0.f, h1 = 0.f, h2 = 0.f, h3 = 0.f;
        for (int k = 0; k < K; k += 4) {   // all K % 4 == 0
            h0 += sp[k]     * W[(size_t)(k)     * 512 + f];
            h1 += sp[k + 1] * W[(size_t)(k + 1) * 512 + f];
            h2 += sp[k + 2] * W[(size_t)(k + 2) * 512 + f];
            h3 += sp[k + 3] * W[(size_t)(k + 3) * 512 + f];
        }
        float h = P.bp[st][f] + ((h0 + h1) + (h2 + h3));

        // LayerNorm over 512 features (ddof=0)
        float s = h, q = h * h;
        #pragma unroll
        for (int off = 32; off > 0; off >>= 1) {
            s += __shfl_down(s, off, 64);
            q += __shfl_down(q, off, 64);
        }
        const int lane = threadIdx.x & 63, wid = threadIdx.x >> 6;
        if (lane == 0) { redS[wid] = s; redQ[wid] = q; }
        __syncthreads();
        if (threadIdx.x == 0) {
            float ts = 0.f, tq = 0.f;
            #pragma unroll
            for (int i = 0; i < 8; ++i) { ts += redS[i]; tq += redQ[i]; }
            float mu  = ts * (1.f / 512.f);
            float var = tq * (1.f / 512.f) - mu * mu;
            s_mu   = mu;
            s_rstd = rsqrtf(var + 1e-5f);
        }
        __syncthreads();

        float x  = (h - s_mu) * s_rstd * P.g[st][f] + P.be[st][f];
        float ge = 0.5f * x * (1.f + erff(x * 0.70710678118654752f));
        acc += wsm[b * 2 + j] * ge;
    }
    mix[(size_t)b * 512 + f] = acc;
}

// ---------------------------------------------------------------------------
extern "C" void kernel_launch(void* const* d_in, const int* in_sizes, int n_in,
                              void* d_out, int out_size, void* d_ws, size_t ws_size,
                              hipStream_t stream) {
    const int B = 256, F = 512, H = 1024, C = 1000;

    const float* s1 = (const float*)d_in[0];
    const float* s2 = (const float*)d_in[1];
    const float* s3 = (const float*)d_in[2];
    const float* s4 = (const float*)d_in[3];
    const float* s5 = (const float*)d_in[4];
    const float* ff = (const float*)d_in[5];
    const float *Wp[5], *bp[5], *g[5], *be[5];
    for (int i = 0; i < 5; ++i) {
        Wp[i] = (const float*)d_in[6 + 4 * i];
        bp[i] = (const float*)d_in[7 + 4 * i];
        g[i]  = (const float*)d_in[8 + 4 * i];
        be[i] = (const float*)d_in[9 + 4 * i];
    }
    const float* Wg1 = (const float*)d_in[26]; const float* bg1 = (const float*)d_in[27];
    const float* Wg2 = (const float*)d_in[28]; const float* bg2 = (const float*)d_in[29];
    const float* Wg3 = (const float*)d_in[30]; const float* bg3 = (const float*)d_in[31];
    const float* Wc1 = (const float*)d_in[32]; const float* bc1 = (const float*)d_in[33];
    const float* Wc2 = (const float*)d_in[34]; const float* bc2 = (const float*)d_in[35];
    const float* Wc3 = (const float*)d_in[36]; const float* bc3 = (const float*)d_in[37];

    // ---- workspace layout (fp32 elements) ----
    float* ws = (float*)d_ws;
    const int Ks[5]   = {16, 24, 40, 80, 160};
    const int poff[5] = {0, 4096, 10240, 20480, 40960};      // B*K prefix sums
    float* pools    = ws;                                     // 81920
    float* gate_in  = ws + 81920;                             // 245760
    float* g1h      = ws + 327680;                            // 262144
    float* g2h      = ws + 589824;                            // 131072
    float* wsm      = ws + 722176;                            // 512
    int*   topi     = (int*)(ws + 722688);                    // 512
    float* mix      = ws + 723200;                            // 131072
    float* c1h      = ws + 854272;                            // 262144
    float* c2h      = ws + 1116416;                           // 131072
    const size_t part_off = 1247488;
    float* partials = ws + part_off;                          // rest of ws

    float* out      = (float*)d_out;
    float* out_gl   = out + 256000;
    float* out_topi = out + 257280;
    float* out_w    = out + 257792;

    // ---- 1a) pooling: big rows (s1..s4), wave per row ----
    Pool4Segs S;
    {
        const float* srcs[4] = { s1, s2, s3, s4 };
        float* dsts[4] = { pools + poff[0], pools + poff[1], pools + poff[2], pools + poff[3] };
        const int rls[4]  = { 112 * 112, 56 * 56, 28 * 28, 14 * 14 };
        const int rows[4] = { B * 16, B * 24, B * 40, B * 80 };
        int cum = 0;
        for (int i = 0; i < 4; ++i) {
            S.src[i] = srcs[i]; S.dst[i] = dsts[i]; S.n4[i] = rls[i] / 4;
            cum += rows[i]; S.cum[i] = cum; S.inv[i] = 1.f / rls[i];
        }
        int blocks = (cum * 64 + 255) / 256;   // cum = 40960 waves
        pool_big_kernel<<<blocks, 256, 0, stream>>>(S, cum);
    }
    // ---- 1b) pooling: rowlen-49 (s5, ff) via LDS staging, 64 rows/block ----
    {
        int rows5 = B * 160;                  // 40960, divisible by 64
        int total = rows5 + B * 960;          // 286720
        pool_small_kernel<<<total / 64, 256, 0, stream>>>(s5, ff, pools + poff[4], gate_in, rows5);
    }

    // split-K FC v2 (ROWS=4): partials then deterministic reduce (+bias,+relu)
    auto fc = [&](const float* X, const float* W, const float* bias, float* Y,
                  int M, int K, int N, int KSwant, int do_relu) {
        int NW = (N + 255) / 256;
        // cap KS by available partial space
        size_t avail = ws_size / 4 > part_off ? ws_size / 4 - part_off : 0;
        int KSmax = (int)(avail / ((size_t)M * N));
        int KS = KSwant; if (KS > KSmax) KS = KSmax; if (KS < 1) KS = 1;
        int Kc = (((K + KS - 1) / KS) + 3) & ~3;     // multiple of 4
        KS = (K + Kc - 1) / Kc;                       // actual slice count
        int waves  = KS * (M / 4) * NW;
        int blocks = (waves * 64 + 255) / 256;
        fc_splitk_kernel<4><<<blocks, 256, 0, stream>>>(X, W, partials, M, K, N, NW, Kc, waves);
        int MN = M * N;
        reduce_bias_kernel<<<(MN / 4 + 255) / 256, 256, 0, stream>>>(
            partials, bias, Y, MN, N, KS, do_relu);
    };

    // ---- 2) gate MLP ----
    fc(gate_in, Wg1, bg1, g1h, B, 960, H, 8, 1);      // 2048 waves, Kc=120
    fc(g1h, Wg2, bg2, g2h, B, H, H / 2, 16, 1);       // 2048 waves, Kc=64
    fc3_top2_kernel<<<B, 256, 0, stream>>>(g2h, Wg3, bg3, topi, wsm,
                                           out_gl, out_topi, out_w, H / 2);

    // ---- 3) selected projections + mixture ----
    ProjParams P;
    for (int i = 0; i < 5; ++i) {
        P.W[i] = Wp[i]; P.bp[i] = bp[i]; P.g[i] = g[i]; P.be[i] = be[i];
        P.K[i] = Ks[i]; P.poff[i] = poff[i];
    }
    proj_mix_kernel<<<B, 512, 0, stream>>>(P, pools, topi, wsm, mix);

    // ---- 4) classifier MLP ----
    fc(mix, Wc1, bc1, c1h, B, F, H, 8, 1);            // 2048 waves, Kc=64
    fc(c1h, Wc2, bc2, c2h, B, H, H / 2, 16, 1);       // 2048 waves, Kc=64
    fc(c2h, Wc3, bc3, out, B, H / 2, C, 8, 0);        // 2048 waves, Kc=64
}

// Round 5
// 584.665 us; speedup vs baseline: 1.2170x; 1.2170x over previous
//
#include <hip/hip_runtime.h>
#include <math.h>

// All tensors fp32. B=256, F=512, H=1024, C=1000.

// ---------------------------------------------------------------------------
// pool_big: wave per row, float4 loads, 8-deep unroll. ~122 us = wall of the
// beyond-L2 read path (~2.7 TB/s combined L3+HBM). Known-good (R2).
// ---------------------------------------------------------------------------
struct Pool4Segs {
    const float* src[4];
    float*       dst[4];
    int n4[4];        // rowlen / 4
    int cum[4];       // inclusive prefix sum of rows
    float inv[4];
};

__global__ __launch_bounds__(256) void pool_big_kernel(Pool4Segs S, int total_waves) {
    int gid  = blockIdx.x * 256 + threadIdx.x;
    int wave = gid >> 6;
    int lane = gid & 63;
    if (wave >= total_waves) return;
    int s = 0;
    #pragma unroll
    for (int i = 0; i < 3; ++i) if (wave >= S.cum[i]) s = i + 1;
    int row = wave - (s == 0 ? 0 : S.cum[s - 1]);
    const int n4 = S.n4[s];
    const float4* p4 = (const float4*)(S.src[s]) + (size_t)row * n4;

    float a0 = 0.f, a1 = 0.f, a2 = 0.f, a3 = 0.f;
    float a4 = 0.f, a5 = 0.f, a6 = 0.f, a7 = 0.f;
    int k = lane;
    for (; k + 448 < n4; k += 512) {
        float4 v0 = p4[k];       float4 v1 = p4[k + 64];
        float4 v2 = p4[k + 128]; float4 v3 = p4[k + 192];
        float4 v4 = p4[k + 256]; float4 v5 = p4[k + 320];
        float4 v6 = p4[k + 384]; float4 v7 = p4[k + 448];
        a0 += (v0.x + v0.y) + (v0.z + v0.w);
        a1 += (v1.x + v1.y) + (v1.z + v1.w);
        a2 += (v2.x + v2.y) + (v2.z + v2.w);
        a3 += (v3.x + v3.y) + (v3.z + v3.w);
        a4 += (v4.x + v4.y) + (v4.z + v4.w);
        a5 += (v5.x + v5.y) + (v5.z + v5.w);
        a6 += (v6.x + v6.y) + (v6.z + v6.w);
        a7 += (v7.x + v7.y) + (v7.z + v7.w);
    }
    for (; k + 192 < n4; k += 256) {
        float4 v0 = p4[k];       float4 v1 = p4[k + 64];
        float4 v2 = p4[k + 128]; float4 v3 = p4[k + 192];
        a0 += (v0.x + v0.y) + (v0.z + v0.w);
        a1 += (v1.x + v1.y) + (v1.z + v1.w);
        a2 += (v2.x + v2.y) + (v2.z + v2.w);
        a3 += (v3.x + v3.y) + (v3.z + v3.w);
    }
    for (; k < n4; k += 64) {
        float4 v = p4[k];
        a0 += (v.x + v.y) + (v.z + v.w);
    }
    float acc = ((a0 + a1) + (a2 + a3)) + ((a4 + a5) + (a6 + a7));
    #pragma unroll
    for (int off = 32; off > 0; off >>= 1) acc += __shfl_down(acc, off, 64);
    if (lane == 0) S.dst[s][row] = acc * S.inv[s];
}

// ---------------------------------------------------------------------------
// pool_small: rowlen == 49 (s5 then ff). Known-good (R2).
// ---------------------------------------------------------------------------
__global__ __launch_bounds__(256) void pool_small_kernel(const float* __restrict__ s5,
        const float* __restrict__ ff, float* __restrict__ dst5, float* __restrict__ dstf,
        int rows5) {
    __shared__ float lds[64 * 49];
    const int tid  = threadIdx.x;
    const int row0 = blockIdx.x * 64;
    const float* src;
    float* dst;
    int rbase;
    if (row0 < rows5) { src = s5; dst = dst5; rbase = row0; }
    else              { src = ff; dst = dstf; rbase = row0 - rows5; }
    const float4* p4 = (const float4*)(src + (size_t)rbase * 49);
    float4* l4 = (float4*)lds;
    float4 v0 = p4[tid];
    float4 v1 = p4[tid + 256];
    float4 v2 = p4[tid + 512];
    float4 v3;
    const bool t3 = (tid < 784 - 768);
    if (t3) v3 = p4[tid + 768];
    l4[tid]       = v0;
    l4[tid + 256] = v1;
    l4[tid + 512] = v2;
    if (t3) l4[tid + 768] = v3;
    __syncthreads();
    const int r  = tid >> 2;
    const int c0 = tid & 3;
    float s = 0.f;
    #pragma unroll
    for (int c = c0; c < 49; c += 4) s += lds[r * 49 + c];
    s += __shfl_down(s, 2, 64);
    s += __shfl_down(s, 1, 64);
    if (c0 == 0) dst[rbase + r] = s * (1.f / 49.f);
}

// ---------------------------------------------------------------------------
// fc_tile: LDS-tiled split-K SGEMM. 256 thr, tile 64m x 64n, TK=8, 4x4 micro
// per thread -> 16 FMA per 2 ds_read_b128. Register-prefetch of next k-tile
// overlaps global latency with the kk-compute. Writes partials P[ks][M][N];
// reduce_bias_kernel sums deterministically (+bias,+relu).
// ---------------------------------------------------------------------------
__global__ __launch_bounds__(256) void fc_tile_kernel(const float* __restrict__ X,
        const float* __restrict__ W, float* __restrict__ P,
        int M, int K, int N, int Kc, int ntiles) {
    __shared__ __align__(16) float Xs[8][68];
    __shared__ __align__(16) float Ws[8][68];
    const int tpk = 4 * ntiles;            // mtiles=4
    int bid = blockIdx.x;
    int ks  = bid / tpk;
    int rem = bid - ks * tpk;
    int mt  = rem / ntiles;
    int nt  = rem - mt * ntiles;
    const int m0 = mt * 64, n0 = nt * 64;
    const int k0 = ks * Kc;
    int k1 = k0 + Kc; if (k1 > K) k1 = K;

    const int tid = threadIdx.x;
    const int tm = tid & 15;               // micro-row group
    const int tn = tid >> 4;               // micro-col group (0..15)
    // staging assignments
    const int xa = tid >> 3, xb = tid & 7; // X[m0+xa(+32)][kt+xb]
    const int wc = tid & 63, wb = tid >> 6;// W[kt+wb(+4)][n0+wc]
    const int nw = n0 + wc;
    const bool wok = (nw < N);

    float4 acc[4];
    #pragma unroll
    for (int r = 0; r < 4; ++r) acc[r] = make_float4(0.f, 0.f, 0.f, 0.f);

    float x0, x1, w0v, w1v;
    // prefetch first tile
    x0  = X[(size_t)(m0 + xa) * K + k0 + xb];
    x1  = X[(size_t)(m0 + xa + 32) * K + k0 + xb];
    w0v = wok ? W[(size_t)(k0 + wb) * N + nw] : 0.f;
    w1v = wok ? W[(size_t)(k0 + wb + 4) * N + nw] : 0.f;

    for (int kt = k0; kt < k1; kt += 8) {
        __syncthreads();
        Xs[xb][xa] = x0; Xs[xb][xa + 32] = x1;
        Ws[wb][wc] = w0v; Ws[wb + 4][wc] = w1v;
        __syncthreads();
        if (kt + 8 < k1) {                 // issue next-tile loads early
            x0  = X[(size_t)(m0 + xa) * K + kt + 8 + xb];
            x1  = X[(size_t)(m0 + xa + 32) * K + kt + 8 + xb];
            w0v = wok ? W[(size_t)(kt + 8 + wb) * N + nw] : 0.f;
            w1v = wok ? W[(size_t)(kt + 8 + wb + 4) * N + nw] : 0.f;
        }
        #pragma unroll
        for (int kk = 0; kk < 8; ++kk) {
            float4 xr = *(const float4*)&Xs[kk][tm * 4];
            float4 wr = *(const float4*)&Ws[kk][tn * 4];
            acc[0].x += xr.x * wr.x; acc[0].y += xr.x * wr.y;
            acc[0].z += xr.x * wr.z; acc[0].w += xr.x * wr.w;
            acc[1].x += xr.y * wr.x; acc[1].y += xr.y * wr.y;
            acc[1].z += xr.y * wr.z; acc[1].w += xr.y * wr.w;
            acc[2].x += xr.z * wr.x; acc[2].y += xr.z * wr.y;
            acc[2].z += xr.z * wr.z; acc[2].w += xr.z * wr.w;
            acc[3].x += xr.w * wr.x; acc[3].y += xr.w * wr.y;
            acc[3].z += xr.w * wr.z; acc[3].w += xr.w * wr.w;
        }
    }
    const int nbase = n0 + tn * 4;
    #pragma unroll
    for (int r = 0; r < 4; ++r) {
        int row = m0 + tm * 4 + r;
        float* pp = P + ((size_t)ks * M + row) * N + nbase;
        if (nbase + 3 < N) {
            *(float4*)pp = acc[r];
        } else {
            float v[4] = { acc[r].x, acc[r].y, acc[r].z, acc[r].w };
            for (int c = 0; c < 4; ++c) if (nbase + c < N) pp[c] = v[c];
        }
    }
}

// Sum KS partial slices + bias (+ReLU). float4 per thread; N % 4 == 0.
__global__ __launch_bounds__(256) void reduce_bias_kernel(const float* __restrict__ P,
        const float* __restrict__ bias, float* __restrict__ Y,
        int MN, int N, int KS, int do_relu) {
    int i = (blockIdx.x * 256 + threadIdx.x) * 4;
    if (i >= MN) return;
    float4 a = *(const float4*)(P + i);
    for (int s = 1; s < KS; ++s) {
        float4 b = *(const float4*)(P + (size_t)s * MN + i);
        a.x += b.x; a.y += b.y; a.z += b.z; a.w += b.w;
    }
    int n = i - (i / N) * N;
    float4 bb = *(const float4*)(bias + n);
    a.x += bb.x; a.y += bb.y; a.z += bb.z; a.w += bb.w;
    if (do_relu) {
        a.x = fmaxf(a.x, 0.f); a.y = fmaxf(a.y, 0.f);
        a.z = fmaxf(a.z, 0.f); a.w = fmaxf(a.w, 0.f);
    }
    *(float4*)(Y + i) = a;
}

// ---------------------------------------------------------------------------
// Batched projection GEMM: all 5 stages in one dispatch. Same tile structure
// as fc_tile, KS=1, bias fused (no relu). grid = (4*8 tiles, 5 stages).
// X_st = pools+poff[st] [256][Kst], W_st [Kst][512], out proj_out+st*131072.
// ---------------------------------------------------------------------------
struct ProjParams {
    const float* W[5];
    const float* bp[5];
    const float* g[5];
    const float* be[5];
    int K[5];
    int poff[5];
};

__global__ __launch_bounds__(256) void proj_gemm_kernel(ProjParams P,
        const float* __restrict__ pools, float* __restrict__ proj_out) {
    __shared__ __align__(16) float Xs[8][68];
    __shared__ __align__(16) float Ws[8][68];
    const int st = blockIdx.y;
    const int K  = P.K[st];
    const float* X = pools + P.poff[st];
    const float* W = P.W[st];
    const int N = 512;
    int bid = blockIdx.x;                  // 0..31: 4 mtiles x 8 ntiles
    int mt  = bid >> 3;
    int nt  = bid & 7;
    const int m0 = mt * 64, n0 = nt * 64;

    const int tid = threadIdx.x;
    const int tm = tid & 15;
    const int tn = tid >> 4;
    const int xa = tid >> 3, xb = tid & 7;
    const int wc = tid & 63, wb = tid >> 6;
    const int nw = n0 + wc;

    float4 acc[4];
    #pragma unroll
    for (int r = 0; r < 4; ++r) acc[r] = make_float4(0.f, 0.f, 0.f, 0.f);

    float x0, x1, w0v, w1v;
    x0  = X[(size_t)(m0 + xa) * K + xb];
    x1  = X[(size_t)(m0 + xa + 32) * K + xb];
    w0v = W[(size_t)wb * N + nw];
    w1v = W[(size_t)(wb + 4) * N + nw];

    for (int kt = 0; kt < K; kt += 8) {
        __syncthreads();
        Xs[xb][xa] = x0; Xs[xb][xa + 32] = x1;
        Ws[wb][wc] = w0v; Ws[wb + 4][wc] = w1v;
        __syncthreads();
        if (kt + 8 < K) {
            x0  = X[(size_t)(m0 + xa) * K + kt + 8 + xb];
            x1  = X[(size_t)(m0 + xa + 32) * K + kt + 8 + xb];
            w0v = W[(size_t)(kt + 8 + wb) * N + nw];
            w1v = W[(size_t)(kt + 8 + wb + 4) * N + nw];
        }
        #pragma unroll
        for (int kk = 0; kk < 8; ++kk) {
            float4 xr = *(const float4*)&Xs[kk][tm * 4];
            float4 wr = *(const float4*)&Ws[kk][tn * 4];
            acc[0].x += xr.x * wr.x; acc[0].y += xr.x * wr.y;
            acc[0].z += xr.x * wr.z; acc[0].w += xr.x * wr.w;
            acc[1].x += xr.y * wr.x; acc[1].y += xr.y * wr.y;
            acc[1].z += xr.y * wr.z; acc[1].w += xr.y * wr.w;
            acc[2].x += xr.z * wr.x; acc[2].y += xr.z * wr.y;
            acc[2].z += xr.z * wr.z; acc[2].w += xr.z * wr.w;
            acc[3].x += xr.w * wr.x; acc[3].y += xr.w * wr.y;
            acc[3].z += xr.w * wr.z; acc[3].w += xr.w * wr.w;
        }
    }
    const int nbase = n0 + tn * 4;
    float4 bb = *(const float4*)(P.bp[st] + nbase);
    float* op = proj_out + (size_t)st * 131072 + (size_t)(m0 + tm * 4) * N + nbase;
    #pragma unroll
    for (int r = 0; r < 4; ++r) {
        float4 v = acc[r];
        v.x += bb.x; v.y += bb.y; v.z += bb.z; v.w += bb.w;
        *(float4*)(op + (size_t)r * N) = v;
    }
}

// ---------------------------------------------------------------------------
// Gate fc3 (K=512 -> 5 logits) fused with top-2 + softmax. 4 waves per batch.
// jax.lax.top_k tie rule: lower index wins on equality (strict >).
// ---------------------------------------------------------------------------
__global__ __launch_bounds__(256) void fc3_top2_kernel(const float* __restrict__ X,
        const float* __restrict__ W, const float* __restrict__ bias,
        int* __restrict__ topi, float* __restrict__ wsm,
        float* __restrict__ out_gl, float* __restrict__ out_topi,
        float* __restrict__ out_w, int K) {
    const int b    = blockIdx.x;
    const int tid  = threadIdx.x;     // 0..255
    const int lane = tid & 63;
    const int wv   = tid >> 6;
    __shared__ float red[4][5];
    const float* x = X + (size_t)b * K;
    float acc[5] = {0.f, 0.f, 0.f, 0.f, 0.f};
    for (int k = tid; k < K; k += 256) {
        float xv = x[k];
        const float* wr = W + (size_t)k * 5;
        acc[0] += xv * wr[0]; acc[1] += xv * wr[1]; acc[2] += xv * wr[2];
        acc[3] += xv * wr[3]; acc[4] += xv * wr[4];
    }
    #pragma unroll
    for (int off = 32; off > 0; off >>= 1) {
        #pragma unroll
        for (int j = 0; j < 5; ++j) acc[j] += __shfl_down(acc[j], off, 64);
    }
    if (lane == 0) {
        #pragma unroll
        for (int j = 0; j < 5; ++j) red[wv][j] = acc[j];
    }
    __syncthreads();
    if (tid == 0) {
        float v[5];
        #pragma unroll
        for (int j = 0; j < 5; ++j)
            v[j] = ((red[0][j] + red[1][j]) + (red[2][j] + red[3][j])) + bias[j];
        int i0 = 0;
        #pragma unroll
        for (int i = 1; i < 5; ++i) if (v[i] > v[i0]) i0 = i;
        int i1 = -1;
        #pragma unroll
        for (int i = 0; i < 5; ++i) {
            if (i == i0) continue;
            if (i1 < 0 || v[i] > v[i1]) i1 = i;
        }
        float e1 = __expf(v[i1] - v[i0]);          // v[i0] is the max
        float inv = 1.f / (1.f + e1);
        float w0 = inv, w1 = e1 * inv;
        topi[b * 2] = i0; topi[b * 2 + 1] = i1;
        wsm[b * 2] = w0;  wsm[b * 2 + 1] = w1;
        #pragma unroll
        for (int j = 0; j < 5; ++j) out_gl[b * 5 + j] = v[j];
        out_topi[b * 2]     = (float)i0;
        out_topi[b * 2 + 1] = (float)i1;
        out_w[b * 2]     = w0;
        out_w[b * 2 + 1] = w1;
    }
}

// ---------------------------------------------------------------------------
// mixln: gather the two selected projections per batch, LayerNorm + exact
// GELU + softmax-weighted sum. One block of 512 per batch element.
// ---------------------------------------------------------------------------
__global__ __launch_bounds__(512) void mixln_kernel(ProjParams P,
        const float* __restrict__ proj_out, const int* __restrict__ topi,
        const float* __restrict__ wsm, float* __restrict__ mix) {
    const int b = blockIdx.x;
    const int f = threadIdx.x;           // 0..511
    __shared__ float redS[8], redQ[8];
    __shared__ float s_mu, s_rstd;

    float acc = 0.f;
    for (int j = 0; j < 2; ++j) {
        __syncthreads();                 // protect red reuse across iterations
        const int st = topi[b * 2 + j];
        float h = proj_out[(size_t)st * 131072 + (size_t)b * 512 + f];

        // LayerNorm over 512 features (ddof=0)
        float s = h, q = h * h;
        #pragma unroll
        for (int off = 32; off > 0; off >>= 1) {
            s += __shfl_down(s, off, 64);
            q += __shfl_down(q, off, 64);
        }
        const int lane = threadIdx.x & 63, wid = threadIdx.x >> 6;
        if (lane == 0) { redS[wid] = s; redQ[wid] = q; }
        __syncthreads();
        if (threadIdx.x == 0) {
            float ts = 0.f, tq = 0.f;
            #pragma unroll
            for (int i = 0; i < 8; ++i) { ts += redS[i]; tq += redQ[i]; }
            float mu  = ts * (1.f / 512.f);
            float var = tq * (1.f / 512.f) - mu * mu;
            s_mu   = mu;
            s_rstd = rsqrtf(var + 1e-5f);
        }
        __syncthreads();

        float x  = (h - s_mu) * s_rstd * P.g[st][f] + P.be[st][f];
        float ge = 0.5f * x * (1.f + erff(x * 0.70710678118654752f));
        acc += wsm[b * 2 + j] * ge;
    }
    mix[(size_t)b * 512 + f] = acc;
}

// ---------------------------------------------------------------------------
extern "C" void kernel_launch(void* const* d_in, const int* in_sizes, int n_in,
                              void* d_out, int out_size, void* d_ws, size_t ws_size,
                              hipStream_t stream) {
    const int B = 256, F = 512, H = 1024, C = 1000;

    const float* s1 = (const float*)d_in[0];
    const float* s2 = (const float*)d_in[1];
    const float* s3 = (const float*)d_in[2];
    const float* s4 = (const float*)d_in[3];
    const float* s5 = (const float*)d_in[4];
    const float* ff = (const float*)d_in[5];
    const float *Wp[5], *bp[5], *g[5], *be[5];
    for (int i = 0; i < 5; ++i) {
        Wp[i] = (const float*)d_in[6 + 4 * i];
        bp[i] = (const float*)d_in[7 + 4 * i];
        g[i]  = (const float*)d_in[8 + 4 * i];
        be[i] = (const float*)d_in[9 + 4 * i];
    }
    const float* Wg1 = (const float*)d_in[26]; const float* bg1 = (const float*)d_in[27];
    const float* Wg2 = (const float*)d_in[28]; const float* bg2 = (const float*)d_in[29];
    const float* Wg3 = (const float*)d_in[30]; const float* bg3 = (const float*)d_in[31];
    const float* Wc1 = (const float*)d_in[32]; const float* bc1 = (const float*)d_in[33];
    const float* Wc2 = (const float*)d_in[34]; const float* bc2 = (const float*)d_in[35];
    const float* Wc3 = (const float*)d_in[36]; const float* bc3 = (const float*)d_in[37];

    // ---- workspace layout (fp32 elements) ----
    float* ws = (float*)d_ws;
    const int Ks[5]   = {16, 24, 40, 80, 160};
    const int poff[5] = {0, 4096, 10240, 20480, 40960};      // B*K prefix sums
    float* pools    = ws;                                     // 81920
    float* gate_in  = ws + 81920;                             // 245760
    float* g1h      = ws + 327680;                            // 262144
    float* g2h      = ws + 589824;                            // 131072
    float* wsm      = ws + 722176;                            // 512
    int*   topi     = (int*)(ws + 722688);                    // 512
    float* mix      = ws + 723200;                            // 131072
    float* c1h      = ws + 854272;                            // 262144
    float* c2h      = ws + 1116416;                           // 131072
    float* proj_out = ws + 1247488;                           // 655360 (5*B*F)
    const size_t part_off = 1902848;
    float* partials = ws + part_off;                          // rest of ws

    float* out      = (float*)d_out;
    float* out_gl   = out + 256000;
    float* out_topi = out + 257280;
    float* out_w    = out + 257792;

    // ---- 1a) pooling: big rows (s1..s4), wave per row ----
    Pool4Segs S;
    {
        const float* srcs[4] = { s1, s2, s3, s4 };
        float* dsts[4] = { pools + poff[0], pools + poff[1], pools + poff[2], pools + poff[3] };
        const int rls[4]  = { 112 * 112, 56 * 56, 28 * 28, 14 * 14 };
        const int rows[4] = { B * 16, B * 24, B * 40, B * 80 };
        int cum = 0;
        for (int i = 0; i < 4; ++i) {
            S.src[i] = srcs[i]; S.dst[i] = dsts[i]; S.n4[i] = rls[i] / 4;
            cum += rows[i]; S.cum[i] = cum; S.inv[i] = 1.f / rls[i];
        }
        int blocks = (cum * 64 + 255) / 256;   // cum = 40960 waves
        pool_big_kernel<<<blocks, 256, 0, stream>>>(S, cum);
    }
    // ---- 1b) pooling: rowlen-49 (s5, ff) via LDS staging, 64 rows/block ----
    {
        int rows5 = B * 160;                  // 40960, divisible by 64
        int total = rows5 + B * 960;          // 286720
        pool_small_kernel<<<total / 64, 256, 0, stream>>>(s5, ff, pools + poff[4], gate_in, rows5);
    }

    // LDS-tiled split-K GEMM + deterministic reduce (+bias,+relu)
    auto fc = [&](const float* X, const float* W, const float* bias, float* Y,
                  int K, int N, int KSwant, int do_relu) {
        const int M = 256;
        int ntiles = (N + 63) / 64;
        size_t avail = ws_size / 4 > part_off ? ws_size / 4 - part_off : 0;
        int KSmax = (int)(avail / ((size_t)M * N));
        int KS = KSwant; if (KS > KSmax) KS = KSmax; if (KS < 1) KS = 1;
        int Kc = (((K + KS - 1) / KS) + 7) & ~7;     // multiple of 8
        KS = (K + Kc - 1) / Kc;                       // actual slice count
        int blocks = KS * 4 * ntiles;
        fc_tile_kernel<<<blocks, 256, 0, stream>>>(X, W, partials, M, K, N, Kc, ntiles);
        int MN = M * N;
        reduce_bias_kernel<<<(MN / 4 + 255) / 256, 256, 0, stream>>>(
            partials, bias, Y, MN, N, KS, do_relu);
    };

    // ---- 2) gate MLP ----
    fc(gate_in, Wg1, bg1, g1h, 960, H, 8, 1);         // 512 blocks, Kc=120
    fc(g1h, Wg2, bg2, g2h, H, H / 2, 16, 1);          // 512 blocks, Kc=64
    fc3_top2_kernel<<<B, 256, 0, stream>>>(g2h, Wg3, bg3, topi, wsm,
                                           out_gl, out_topi, out_w, H / 2);

    // ---- 3) all 5 projections (batched GEMM), then gather+LN+GELU+mix ----
    ProjParams P;
    for (int i = 0; i < 5; ++i) {
        P.W[i] = Wp[i]; P.bp[i] = bp[i]; P.g[i] = g[i]; P.be[i] = be[i];
        P.K[i] = Ks[i]; P.poff[i] = poff[i];
    }
    proj_gemm_kernel<<<dim3(32, 5), 256, 0, stream>>>(P, pools, proj_out);
    mixln_kernel<<<B, 512, 0, stream>>>(P, proj_out, topi, wsm, mix);

    // ---- 4) classifier MLP ----
    fc(mix, Wc1, bc1, c1h, F, H, 8, 1);               // 512 blocks, Kc=64
    fc(c1h, Wc2, bc2, c2h, H, H / 2, 16, 1);          // 512 blocks, Kc=64
    fc(c2h, Wc3, bc3, out, H / 2, C, 8, 0);           // 512 blocks, Kc=64
}

// Round 6
// 571.901 us; speedup vs baseline: 1.2442x; 1.0223x over previous
//
#include <hip/hip_runtime.h>
#include <math.h>

// All tensors fp32. B=256, F=512, H=1024, C=1000.

// ---------------------------------------------------------------------------
// pool_big: wave per row, float4 loads, 8-deep unroll. ~2.7 TB/s combined
// L3+HBM read wall (122 us for all four segs). Launched as TWO dispatches
// (s1 | s2..s4) so the top-5 profile cutoff drops to ~65 us and the FC stack
// becomes visible. Per-wave code unchanged (known-good R2).
// ---------------------------------------------------------------------------
struct Pool4Segs {
    const float* src[4];
    float*       dst[4];
    int n4[4];        // rowlen / 4
    int cum[4];       // inclusive prefix sum of rows
    float inv[4];
};

__global__ __launch_bounds__(256) void pool_big_kernel(Pool4Segs S, int total_waves) {
    int gid  = blockIdx.x * 256 + threadIdx.x;
    int wave = gid >> 6;
    int lane = gid & 63;
    if (wave >= total_waves) return;
    int s = 0;
    #pragma unroll
    for (int i = 0; i < 3; ++i) if (wave >= S.cum[i]) s = i + 1;
    int row = wave - (s == 0 ? 0 : S.cum[s - 1]);
    const int n4 = S.n4[s];
    const float4* p4 = (const float4*)(S.src[s]) + (size_t)row * n4;

    float a0 = 0.f, a1 = 0.f, a2 = 0.f, a3 = 0.f;
    float a4 = 0.f, a5 = 0.f, a6 = 0.f, a7 = 0.f;
    int k = lane;
    for (; k + 448 < n4; k += 512) {
        float4 v0 = p4[k];       float4 v1 = p4[k + 64];
        float4 v2 = p4[k + 128]; float4 v3 = p4[k + 192];
        float4 v4 = p4[k + 256]; float4 v5 = p4[k + 320];
        float4 v6 = p4[k + 384]; float4 v7 = p4[k + 448];
        a0 += (v0.x + v0.y) + (v0.z + v0.w);
        a1 += (v1.x + v1.y) + (v1.z + v1.w);
        a2 += (v2.x + v2.y) + (v2.z + v2.w);
        a3 += (v3.x + v3.y) + (v3.z + v3.w);
        a4 += (v4.x + v4.y) + (v4.z + v4.w);
        a5 += (v5.x + v5.y) + (v5.z + v5.w);
        a6 += (v6.x + v6.y) + (v6.z + v6.w);
        a7 += (v7.x + v7.y) + (v7.z + v7.w);
    }
    for (; k + 192 < n4; k += 256) {
        float4 v0 = p4[k];       float4 v1 = p4[k + 64];
        float4 v2 = p4[k + 128]; float4 v3 = p4[k + 192];
        a0 += (v0.x + v0.y) + (v0.z + v0.w);
        a1 += (v1.x + v1.y) + (v1.z + v1.w);
        a2 += (v2.x + v2.y) + (v2.z + v2.w);
        a3 += (v3.x + v3.y) + (v3.z + v3.w);
    }
    for (; k < n4; k += 64) {
        float4 v = p4[k];
        a0 += (v.x + v.y) + (v.z + v.w);
    }
    float acc = ((a0 + a1) + (a2 + a3)) + ((a4 + a5) + (a6 + a7));
    #pragma unroll
    for (int off = 32; off > 0; off >>= 1) acc += __shfl_down(acc, off, 64);
    if (lane == 0) S.dst[s][row] = acc * S.inv[s];
}

// ---------------------------------------------------------------------------
// pool_small: rowlen == 49 (s5 then ff). Known-good (R2).
// ---------------------------------------------------------------------------
__global__ __launch_bounds__(256) void pool_small_kernel(const float* __restrict__ s5,
        const float* __restrict__ ff, float* __restrict__ dst5, float* __restrict__ dstf,
        int rows5) {
    __shared__ float lds[64 * 49];
    const int tid  = threadIdx.x;
    const int row0 = blockIdx.x * 64;
    const float* src;
    float* dst;
    int rbase;
    if (row0 < rows5) { src = s5; dst = dst5; rbase = row0; }
    else              { src = ff; dst = dstf; rbase = row0 - rows5; }
    const float4* p4 = (const float4*)(src + (size_t)rbase * 49);
    float4* l4 = (float4*)lds;
    float4 v0 = p4[tid];
    float4 v1 = p4[tid + 256];
    float4 v2 = p4[tid + 512];
    float4 v3;
    const bool t3 = (tid < 784 - 768);
    if (t3) v3 = p4[tid + 768];
    l4[tid]       = v0;
    l4[tid + 256] = v1;
    l4[tid + 512] = v2;
    if (t3) l4[tid + 768] = v3;
    __syncthreads();
    const int r  = tid >> 2;
    const int c0 = tid & 3;
    float s = 0.f;
    #pragma unroll
    for (int c = c0; c < 49; c += 4) s += lds[r * 49 + c];
    s += __shfl_down(s, 2, 64);
    s += __shfl_down(s, 1, 64);
    if (c0 == 0) dst[rbase + r] = s * (1.f / 49.f);
}

// ---------------------------------------------------------------------------
// fc_tile v2: LDS-tiled split-K SGEMM. 256 thr, tile 64m x 64n, TK=16,
// float4 staging loads on BOTH operands (16 B/lane coalescing), 4x4 micro
// per thread. 2 barriers per 16-deep K-step (half of v1), 256 FMA between
// barriers. Register prefetch of the next K-step overlaps global latency.
// Requires Kc (slice length) % 16 == 0 (host guarantees), K % 4 == 0.
// Writes partials P[ks][M][N]; reduce_bias_kernel sums deterministically.
// ---------------------------------------------------------------------------
__global__ __launch_bounds__(256) void fc_tile_kernel(const float* __restrict__ X,
        const float* __restrict__ W, float* __restrict__ P,
        int M, int K, int N, int Kc, int ntiles) {
    __shared__ __align__(16) float Xs[16][68];   // [k][m]
    __shared__ __align__(16) float Ws[16][68];   // [k][n]
    const int tpk = 4 * ntiles;            // mtiles=4
    int bid = blockIdx.x;
    int ks  = bid / tpk;
    int rem = bid - ks * tpk;
    int mt  = rem / ntiles;
    int nt  = rem - mt * ntiles;
    const int m0 = mt * 64, n0 = nt * 64;
    const int k0 = ks * Kc;
    int k1 = k0 + Kc; if (k1 > K) k1 = K;

    const int tid = threadIdx.x;
    const int tm = tid & 15;               // micro-row group
    const int tn = tid >> 4;               // micro-col group (0..15)
    // X staging: thread -> X[m0+xr][k + xc*4 .. +3] (float4, coalesced in k)
    const int xr = tid >> 2, xc = tid & 3;
    // W staging: thread -> W[k + wr][n0 + wc*4 .. +3] (float4, coalesced in n)
    const int wr = tid >> 4, wc = tid & 15;
    const int nwc = n0 + wc * 4;

    float4 acc[4];
    #pragma unroll
    for (int r = 0; r < 4; ++r) acc[r] = make_float4(0.f, 0.f, 0.f, 0.f);

    float4 xv, wv;
    // prefetch first K-step
    xv = *(const float4*)(X + (size_t)(m0 + xr) * K + k0 + xc * 4);
    if (nwc + 3 < N) {
        wv = *(const float4*)(W + (size_t)(k0 + wr) * N + nwc);
    } else {
        wv.x = (nwc + 0 < N) ? W[(size_t)(k0 + wr) * N + nwc + 0] : 0.f;
        wv.y = (nwc + 1 < N) ? W[(size_t)(k0 + wr) * N + nwc + 1] : 0.f;
        wv.z = (nwc + 2 < N) ? W[(size_t)(k0 + wr) * N + nwc + 2] : 0.f;
        wv.w = (nwc + 3 < N) ? W[(size_t)(k0 + wr) * N + nwc + 3] : 0.f;
    }

    for (int kt = k0; kt < k1; kt += 16) {
        __syncthreads();
        // X: transpose into [k][m] (4 scalar writes, <=2-way bank alias = free)
        Xs[xc * 4 + 0][xr] = xv.x;
        Xs[xc * 4 + 1][xr] = xv.y;
        Xs[xc * 4 + 2][xr] = xv.z;
        Xs[xc * 4 + 3][xr] = xv.w;
        *(float4*)&Ws[wr][wc * 4] = wv;
        __syncthreads();
        if (kt + 16 < k1) {                // issue next-step loads early
            xv = *(const float4*)(X + (size_t)(m0 + xr) * K + kt + 16 + xc * 4);
            if (nwc + 3 < N) {
                wv = *(const float4*)(W + (size_t)(kt + 16 + wr) * N + nwc);
            } else {
                wv.x = (nwc + 0 < N) ? W[(size_t)(kt + 16 + wr) * N + nwc + 0] : 0.f;
                wv.y = (nwc + 1 < N) ? W[(size_t)(kt + 16 + wr) * N + nwc + 1] : 0.f;
                wv.z = (nwc + 2 < N) ? W[(size_t)(kt + 16 + wr) * N + nwc + 2] : 0.f;
                wv.w = (nwc + 3 < N) ? W[(size_t)(kt + 16 + wr) * N + nwc + 3] : 0.f;
            }
        }
        #pragma unroll
        for (int kk = 0; kk < 16; ++kk) {
            float4 xr4 = *(const float4*)&Xs[kk][tm * 4];
            float4 wr4 = *(const float4*)&Ws[kk][tn * 4];
            acc[0].x += xr4.x * wr4.x; acc[0].y += xr4.x * wr4.y;
            acc[0].z += xr4.x * wr4.z; acc[0].w += xr4.x * wr4.w;
            acc[1].x += xr4.y * wr4.x; acc[1].y += xr4.y * wr4.y;
            acc[1].z += xr4.y * wr4.z; acc[1].w += xr4.y * wr4.w;
            acc[2].x += xr4.z * wr4.x; acc[2].y += xr4.z * wr4.y;
            acc[2].z += xr4.z * wr4.z; acc[2].w += xr4.z * wr4.w;
            acc[3].x += xr4.w * wr4.x; acc[3].y += xr4.w * wr4.y;
            acc[3].z += xr4.w * wr4.z; acc[3].w += xr4.w * wr4.w;
        }
    }
    const int nbase = n0 + tn * 4;
    #pragma unroll
    for (int r = 0; r < 4; ++r) {
        int row = m0 + tm * 4 + r;
        float* pp = P + ((size_t)ks * M + row) * N + nbase;
        if (nbase + 3 < N) {
            *(float4*)pp = acc[r];
        } else {
            float v[4] = { acc[r].x, acc[r].y, acc[r].z, acc[r].w };
            for (int c = 0; c < 4; ++c) if (nbase + c < N) pp[c] = v[c];
        }
    }
}

// Sum KS partial slices + bias (+ReLU). float4 per thread; N % 4 == 0.
__global__ __launch_bounds__(256) void reduce_bias_kernel(const float* __restrict__ P,
        const float* __restrict__ bias, float* __restrict__ Y,
        int MN, int N, int KS, int do_relu) {
    int i = (blockIdx.x * 256 + threadIdx.x) * 4;
    if (i >= MN) return;
    float4 a = *(const float4*)(P + i);
    for (int s = 1; s < KS; ++s) {
        float4 b = *(const float4*)(P + (size_t)s * MN + i);
        a.x += b.x; a.y += b.y; a.z += b.z; a.w += b.w;
    }
    int n = i - (i / N) * N;
    float4 bb = *(const float4*)(bias + n);
    a.x += bb.x; a.y += bb.y; a.z += bb.z; a.w += bb.w;
    if (do_relu) {
        a.x = fmaxf(a.x, 0.f); a.y = fmaxf(a.y, 0.f);
        a.z = fmaxf(a.z, 0.f); a.w = fmaxf(a.w, 0.f);
    }
    *(float4*)(Y + i) = a;
}

// ---------------------------------------------------------------------------
// Batched projection GEMM: all 5 stages in one dispatch (TK=8 variant, K is
// small: 16..160). grid = (32 tiles, 5 stages). Bias fused.
// ---------------------------------------------------------------------------
struct ProjParams {
    const float* W[5];
    const float* bp[5];
    const float* g[5];
    const float* be[5];
    int K[5];
    int poff[5];
};

__global__ __launch_bounds__(256) void proj_gemm_kernel(ProjParams P,
        const float* __restrict__ pools, float* __restrict__ proj_out) {
    __shared__ __align__(16) float Xs[8][68];
    __shared__ __align__(16) float Ws[8][68];
    const int st = blockIdx.y;
    const int K  = P.K[st];
    const float* X = pools + P.poff[st];
    const float* W = P.W[st];
    const int N = 512;
    int bid = blockIdx.x;                  // 0..31: 4 mtiles x 8 ntiles
    int mt  = bid >> 3;
    int nt  = bid & 7;
    const int m0 = mt * 64, n0 = nt * 64;

    const int tid = threadIdx.x;
    const int tm = tid & 15;
    const int tn = tid >> 4;
    const int xa = tid >> 3, xb = tid & 7;
    const int wc = tid & 63, wb = tid >> 6;
    const int nw = n0 + wc;

    float4 acc[4];
    #pragma unroll
    for (int r = 0; r < 4; ++r) acc[r] = make_float4(0.f, 0.f, 0.f, 0.f);

    float x0, x1, w0v, w1v;
    x0  = X[(size_t)(m0 + xa) * K + xb];
    x1  = X[(size_t)(m0 + xa + 32) * K + xb];
    w0v = W[(size_t)wb * N + nw];
    w1v = W[(size_t)(wb + 4) * N + nw];

    for (int kt = 0; kt < K; kt += 8) {
        __syncthreads();
        Xs[xb][xa] = x0; Xs[xb][xa + 32] = x1;
        Ws[wb][wc] = w0v; Ws[wb + 4][wc] = w1v;
        __syncthreads();
        if (kt + 8 < K) {
            x0  = X[(size_t)(m0 + xa) * K + kt + 8 + xb];
            x1  = X[(size_t)(m0 + xa + 32) * K + kt + 8 + xb];
            w0v = W[(size_t)(kt + 8 + wb) * N + nw];
            w1v = W[(size_t)(kt + 8 + wb + 4) * N + nw];
        }
        #pragma unroll
        for (int kk = 0; kk < 8; ++kk) {
            float4 xr = *(const float4*)&Xs[kk][tm * 4];
            float4 wr = *(const float4*)&Ws[kk][tn * 4];
            acc[0].x += xr.x * wr.x; acc[0].y += xr.x * wr.y;
            acc[0].z += xr.x * wr.z; acc[0].w += xr.x * wr.w;
            acc[1].x += xr.y * wr.x; acc[1].y += xr.y * wr.y;
            acc[1].z += xr.y * wr.z; acc[1].w += xr.y * wr.w;
            acc[2].x += xr.z * wr.x; acc[2].y += xr.z * wr.y;
            acc[2].z += xr.z * wr.z; acc[2].w += xr.z * wr.w;
            acc[3].x += xr.w * wr.x; acc[3].y += xr.w * wr.y;
            acc[3].z += xr.w * wr.z; acc[3].w += xr.w * wr.w;
        }
    }
    const int nbase = n0 + tn * 4;
    float4 bb = *(const float4*)(P.bp[st] + nbase);
    float* op = proj_out + (size_t)st * 131072 + (size_t)(m0 + tm * 4) * N + nbase;
    #pragma unroll
    for (int r = 0; r < 4; ++r) {
        float4 v = acc[r];
        v.x += bb.x; v.y += bb.y; v.z += bb.z; v.w += bb.w;
        *(float4*)(op + (size_t)r * N) = v;
    }
}

// ---------------------------------------------------------------------------
// Gate fc3 (K=512 -> 5 logits) fused with top-2 + softmax. 4 waves per batch.
// jax.lax.top_k tie rule: lower index wins on equality (strict >).
// ---------------------------------------------------------------------------
__global__ __launch_bounds__(256) void fc3_top2_kernel(const float* __restrict__ X,
        const float* __restrict__ W, const float* __restrict__ bias,
        int* __restrict__ topi, float* __restrict__ wsm,
        float* __restrict__ out_gl, float* __restrict__ out_topi,
        float* __restrict__ out_w, int K) {
    const int b    = blockIdx.x;
    const int tid  = threadIdx.x;     // 0..255
    const int lane = tid & 63;
    const int wv   = tid >> 6;
    __shared__ float red[4][5];
    const float* x = X + (size_t)b * K;
    float acc[5] = {0.f, 0.f, 0.f, 0.f, 0.f};
    for (int k = tid; k < K; k += 256) {
        float xv = x[k];
        const float* wr = W + (size_t)k * 5;
        acc[0] += xv * wr[0]; acc[1] += xv * wr[1]; acc[2] += xv * wr[2];
        acc[3] += xv * wr[3]; acc[4] += xv * wr[4];
    }
    #pragma unroll
    for (int off = 32; off > 0; off >>= 1) {
        #pragma unroll
        for (int j = 0; j < 5; ++j) acc[j] += __shfl_down(acc[j], off, 64);
    }
    if (lane == 0) {
        #pragma unroll
        for (int j = 0; j < 5; ++j) red[wv][j] = acc[j];
    }
    __syncthreads();
    if (tid == 0) {
        float v[5];
        #pragma unroll
        for (int j = 0; j < 5; ++j)
            v[j] = ((red[0][j] + red[1][j]) + (red[2][j] + red[3][j])) + bias[j];
        int i0 = 0;
        #pragma unroll
        for (int i = 1; i < 5; ++i) if (v[i] > v[i0]) i0 = i;
        int i1 = -1;
        #pragma unroll
        for (int i = 0; i < 5; ++i) {
            if (i == i0) continue;
            if (i1 < 0 || v[i] > v[i1]) i1 = i;
        }
        float e1 = __expf(v[i1] - v[i0]);          // v[i0] is the max
        float inv = 1.f / (1.f + e1);
        float w0 = inv, w1 = e1 * inv;
        topi[b * 2] = i0; topi[b * 2 + 1] = i1;
        wsm[b * 2] = w0;  wsm[b * 2 + 1] = w1;
        #pragma unroll
        for (int j = 0; j < 5; ++j) out_gl[b * 5 + j] = v[j];
        out_topi[b * 2]     = (float)i0;
        out_topi[b * 2 + 1] = (float)i1;
        out_w[b * 2]     = w0;
        out_w[b * 2 + 1] = w1;
    }
}

// ---------------------------------------------------------------------------
// mixln: gather the two selected projections per batch, LayerNorm + exact
// GELU + softmax-weighted sum. One block of 512 per batch element.
// ---------------------------------------------------------------------------
__global__ __launch_bounds__(512) void mixln_kernel(ProjParams P,
        const float* __restrict__ proj_out, const int* __restrict__ topi,
        const float* __restrict__ wsm, float* __restrict__ mix) {
    const int b = blockIdx.x;
    const int f = threadIdx.x;           // 0..511
    __shared__ float redS[8], redQ[8];
    __shared__ float s_mu, s_rstd;

    float acc = 0.f;
    for (int j = 0; j < 2; ++j) {
        __syncthreads();                 // protect red reuse across iterations
        const int st = topi[b * 2 + j];
        float h = proj_out[(size_t)st * 131072 + (size_t)b * 512 + f];

        // LayerNorm over 512 features (ddof=0)
        float s = h, q = h * h;
        #pragma unroll
        for (int off = 32; off > 0; off >>= 1) {
            s += __shfl_down(s, off, 64);
            q += __shfl_down(q, off, 64);
        }
        const int lane = threadIdx.x & 63, wid = threadIdx.x >> 6;
        if (lane == 0) { redS[wid] = s; redQ[wid] = q; }
        __syncthreads();
        if (threadIdx.x == 0) {
            float ts = 0.f, tq = 0.f;
            #pragma unroll
            for (int i = 0; i < 8; ++i) { ts += redS[i]; tq += redQ[i]; }
            float mu  = ts * (1.f / 512.f);
            float var = tq * (1.f / 512.f) - mu * mu;
            s_mu   = mu;
            s_rstd = rsqrtf(var + 1e-5f);
        }
        __syncthreads();

        float x  = (h - s_mu) * s_rstd * P.g[st][f] + P.be[st][f];
        float ge = 0.5f * x * (1.f + erff(x * 0.70710678118654752f));
        acc += wsm[b * 2 + j] * ge;
    }
    mix[(size_t)b * 512 + f] = acc;
}

// ---------------------------------------------------------------------------
extern "C" void kernel_launch(void* const* d_in, const int* in_sizes, int n_in,
                              void* d_out, int out_size, void* d_ws, size_t ws_size,
                              hipStream_t stream) {
    const int B = 256, F = 512, H = 1024, C = 1000;

    const float* s1 = (const float*)d_in[0];
    const float* s2 = (const float*)d_in[1];
    const float* s3 = (const float*)d_in[2];
    const float* s4 = (const float*)d_in[3];
    const float* s5 = (const float*)d_in[4];
    const float* ff = (const float*)d_in[5];
    const float *Wp[5], *bp[5], *g[5], *be[5];
    for (int i = 0; i < 5; ++i) {
        Wp[i] = (const float*)d_in[6 + 4 * i];
        bp[i] = (const float*)d_in[7 + 4 * i];
        g[i]  = (const float*)d_in[8 + 4 * i];
        be[i] = (const float*)d_in[9 + 4 * i];
    }
    const float* Wg1 = (const float*)d_in[26]; const float* bg1 = (const float*)d_in[27];
    const float* Wg2 = (const float*)d_in[28]; const float* bg2 = (const float*)d_in[29];
    const float* Wg3 = (const float*)d_in[30]; const float* bg3 = (const float*)d_in[31];
    const float* Wc1 = (const float*)d_in[32]; const float* bc1 = (const float*)d_in[33];
    const float* Wc2 = (const float*)d_in[34]; const float* bc2 = (const float*)d_in[35];
    const float* Wc3 = (const float*)d_in[36]; const float* bc3 = (const float*)d_in[37];

    // ---- workspace layout (fp32 elements) ----
    float* ws = (float*)d_ws;
    const int Ks[5]   = {16, 24, 40, 80, 160};
    const int poff[5] = {0, 4096, 10240, 20480, 40960};      // B*K prefix sums
    float* pools    = ws;                                     // 81920
    float* gate_in  = ws + 81920;                             // 245760
    float* g1h      = ws + 327680;                            // 262144
    float* g2h      = ws + 589824;                            // 131072
    float* wsm      = ws + 722176;                            // 512
    int*   topi     = (int*)(ws + 722688);                    // 512
    float* mix      = ws + 723200;                            // 131072
    float* c1h      = ws + 854272;                            // 262144
    float* c2h      = ws + 1116416;                           // 131072
    float* proj_out = ws + 1247488;                           // 655360 (5*B*F)
    const size_t part_off = 1902848;
    float* partials = ws + part_off;                          // rest of ws

    float* out      = (float*)d_out;
    float* out_gl   = out + 256000;
    float* out_topi = out + 257280;
    float* out_w    = out + 257792;

    // ---- 1a) pooling: big rows, TWO dispatches: {s1} then {s2,s3,s4} ----
    {
        Pool4Segs Sa;
        for (int i = 0; i < 4; ++i) {
            Sa.src[i] = s1; Sa.dst[i] = pools + poff[0];
            Sa.n4[i] = 112 * 112 / 4; Sa.cum[i] = B * 16; Sa.inv[i] = 1.f / (112 * 112);
        }
        int waves_a = B * 16;                 // 4096
        pool_big_kernel<<<(waves_a * 64 + 255) / 256, 256, 0, stream>>>(Sa, waves_a);

        Pool4Segs Sb;
        const float* srcs[3] = { s2, s3, s4 };
        float* dsts[3] = { pools + poff[1], pools + poff[2], pools + poff[3] };
        const int rls[3]  = { 56 * 56, 28 * 28, 14 * 14 };
        const int rows[3] = { B * 24, B * 40, B * 80 };
        int cum = 0;
        for (int i = 0; i < 3; ++i) {
            Sb.src[i] = srcs[i]; Sb.dst[i] = dsts[i]; Sb.n4[i] = rls[i] / 4;
            cum += rows[i]; Sb.cum[i] = cum; Sb.inv[i] = 1.f / rls[i];
        }
        Sb.src[3] = srcs[2]; Sb.dst[3] = dsts[2]; Sb.n4[3] = rls[2] / 4;
        Sb.cum[3] = cum; Sb.inv[3] = 1.f / rls[2];
        pool_big_kernel<<<(cum * 64 + 255) / 256, 256, 0, stream>>>(Sb, cum);
    }
    // ---- 1b) pooling: rowlen-49 (s5, ff) via LDS staging, 64 rows/block ----
    {
        int rows5 = B * 160;                  // 40960, divisible by 64
        int total = rows5 + B * 960;          // 286720
        pool_small_kernel<<<total / 64, 256, 0, stream>>>(s5, ff, pools + poff[4], gate_in, rows5);
    }

    // LDS-tiled split-K GEMM (TK=16) + deterministic reduce (+bias,+relu)
    auto fc = [&](const float* X, const float* W, const float* bias, float* Y,
                  int K, int N, int KSwant, int do_relu) {
        const int M = 256;
        int ntiles = (N + 63) / 64;
        size_t avail = ws_size / 4 > part_off ? ws_size / 4 - part_off : 0;
        int KSmax = (int)(avail / ((size_t)M * N));
        int KS = KSwant; if (KS > KSmax) KS = KSmax; if (KS < 1) KS = 1;
        int Kc = (((K + KS - 1) / KS) + 15) & ~15;   // multiple of 16
        KS = (K + Kc - 1) / Kc;                       // actual slice count
        int blocks = KS * 4 * ntiles;
        fc_tile_kernel<<<blocks, 256, 0, stream>>>(X, W, partials, M, K, N, Kc, ntiles);
        int MN = M * N;
        reduce_bias_kernel<<<(MN / 4 + 255) / 256, 256, 0, stream>>>(
            partials, bias, Y, MN, N, KS, do_relu);
    };

    // ---- 2) gate MLP ----
    fc(gate_in, Wg1, bg1, g1h, 960, H, 8, 1);         // Kc=128, KS=8, 512 blocks
    fc(g1h, Wg2, bg2, g2h, H, H / 2, 16, 1);          // Kc=64, KS=16, 512 blocks
    fc3_top2_kernel<<<B, 256, 0, stream>>>(g2h, Wg3, bg3, topi, wsm,
                                           out_gl, out_topi, out_w, H / 2);

    // ---- 3) all 5 projections (batched GEMM), then gather+LN+GELU+mix ----
    ProjParams P;
    for (int i = 0; i < 5; ++i) {
        P.W[i] = Wp[i]; P.bp[i] = bp[i]; P.g[i] = g[i]; P.be[i] = be[i];
        P.K[i] = Ks[i]; P.poff[i] = poff[i];
    }
    proj_gemm_kernel<<<dim3(32, 5), 256, 0, stream>>>(P, pools, proj_out);
    mixln_kernel<<<B, 512, 0, stream>>>(P, proj_out, topi, wsm, mix);

    // ---- 4) classifier MLP ----
    fc(mix, Wc1, bc1, c1h, F, H, 8, 1);               // Kc=64, KS=8, 512 blocks
    fc(c1h, Wc2, bc2, c2h, H, H / 2, 16, 1);          // Kc=64, KS=16, 512 blocks
    fc(c2h, Wc3, bc3, out, H / 2, C, 8, 0);           // Kc=64, KS=8, 512 blocks
}